// Round 20
// baseline (357.131 us; speedup 1.0000x reference)
//
#include <hip/hip_runtime.h>
#include <hip/hip_fp16.h>

#define NCH 128

typedef short bf16x8 __attribute__((ext_vector_type(8)));
typedef float f32x4 __attribute__((ext_vector_type(4)));

__device__ __forceinline__ unsigned short f32_to_bf16_rne(float f) {
    unsigned u = __float_as_uint(f);
    unsigned r = u + 0x7FFFu + ((u >> 16) & 1u);
    return (unsigned short)(r >> 16);
}
// trunc-split: hi = trunc16(f), lo = rne(f - hi). |lo| <= 2^-8|f|.
__device__ __forceinline__ void split_bf16(float f, unsigned short& hi, unsigned short& lo) {
    unsigned u = __float_as_uint(f);
    hi = (unsigned short)(u >> 16);
    float l = f - __uint_as_float(u & 0xFFFF0000u);
    lo = f32_to_bf16_rne(l);
}

// ---------------- fused prep: f2h + degree-count + weight-pack in ONE launch ----------------
// Three fully independent jobs (disjoint outputs) routed by blockIdx range:
//   blocks [0, n4b)           : x -> fp16 (xh)
//   blocks [n4b, n4b+degb)    : degree histogram into off[d+1] (atomics)
//   blocks [n4b+degb, ...)    : pack all weights to bf16 hi/lo MFMA fragment order
__global__ void gin_prep_kernel(const float* __restrict__ x, __half* __restrict__ xh,
                                int n4b, int n4,
                                const int* __restrict__ dst, int* __restrict__ off,
                                int degb, int E,
                                const float* __restrict__ w1s, const float* __restrict__ w2s,
                                const float* __restrict__ wf1, const float* __restrict__ wf2,
                                unsigned short* __restrict__ pw1, unsigned short* __restrict__ pw2,
                                unsigned short* __restrict__ pwf1, unsigned short* __restrict__ pwf2) {
    int b = blockIdx.x;
    int t = threadIdx.x;
    if (b < n4b) {
        int i = b * 256 + t;
        if (i < n4) {
            float4 v = ((const float4*)x)[i];
            union { __half h[4]; uint2 u; } o;
            o.h[0] = __float2half(v.x); o.h[1] = __float2half(v.y);
            o.h[2] = __float2half(v.z); o.h[3] = __float2half(v.w);
            ((uint2*)xh)[i] = o.u;
        }
        return;
    }
    b -= n4b;
    if (b < degb) {
        int e = b * 256 + t;
        if (e < E) atomicAdd(&off[dst[e] + 1], 1);
        return;
    }
    b -= degb;
    int idx = b * 256 + t;
    const float* W; unsigned short* out; int K, N, e;
    if (idx < 98304) {
        int layer = idx >> 15; e = idx & 32767;
        W = w1s + (size_t)layer * 16384; out = pw1 + (size_t)layer * 32768; K = 128; N = 128;
    } else if (idx < 196608) {
        int j = idx - 98304; int layer = j >> 15; e = j & 32767;
        W = w2s + (size_t)layer * 16384; out = pw2 + (size_t)layer * 32768; K = 128; N = 128;
    } else if (idx < 212992) {
        e = idx - 196608; W = wf1; out = pwf1; K = 128; N = 64;
    } else if (idx < 221184) {
        e = idx - 212992; W = wf2; out = pwf2; K = 64; N = 64;
    } else return;
    int KC = K / 32, NT = N / 16;
    int j = e & 7;
    int l = (e >> 3) & 63;
    int v = e >> 9;
    int nt = v % NT; v /= NT;
    int kc = v % KC;
    int spl = v / KC;
    int k = kc * 32 + (l >> 4) * 8 + j;
    int n = nt * 16 + (l & 15);
    float w = W[(size_t)k * N + n];
    unsigned short hi, lo;
    split_bf16(w, hi, lo);
    out[e] = (spl == 0) ? hi : lo;
}

// ---------------- CSR scan (off[d] = start of node d; fill makes it inclusive end) ----------------

// scan1 + degree histogram fused (off[idx] pre-scan IS degree of node idx-1 for idx>=1)
__global__ void gin_scan1(const int* __restrict__ off, int* __restrict__ part,
                          int* __restrict__ hist, int n) {
    __shared__ int red[256];
    __shared__ int lh[64];
    int t = threadIdx.x;
    if (t < 64) lh[t] = 0;
    __syncthreads();
    int base = blockIdx.x * 2048 + t * 8;
    int s = 0;
    for (int i = 0; i < 8; ++i) {
        int idx = base + i;
        if (idx < n) {
            int v = off[idx];
            s += v;
            if (idx > 0) atomicAdd(&lh[min(v, 63)], 1);
        }
    }
    red[t] = s;
    __syncthreads();
    #pragma unroll
    for (int o = 128; o > 0; o >>= 1) {
        if (t < o) red[t] += red[t + o];
        __syncthreads();
    }
    if (t == 0) part[blockIdx.x] = red[0];
    if (t < 64 && lh[t]) atomicAdd(&hist[t], lh[t]);
}

// exclusive scan of part[0..nb-1] in place (nb <= 256)
__global__ void gin_scan2(int* __restrict__ part, int nb) {
    __shared__ int sh[256];
    int t = threadIdx.x;
    int v = (t < nb) ? part[t] : 0;
    sh[t] = v;
    __syncthreads();
    #pragma unroll
    for (int o = 1; o < 256; o <<= 1) {
        int u = (t >= o) ? sh[t - o] : 0;
        __syncthreads();
        sh[t] += u;
        __syncthreads();
    }
    if (t < nb) part[t] = sh[t] - v;
}

__global__ void gin_scan3(int* __restrict__ off, const int* __restrict__ part, int n) {
    __shared__ int red[256];
    int t = threadIdx.x;
    int base = blockIdx.x * 2048 + t * 8;
    int loc[8];
    int s = 0;
    #pragma unroll
    for (int i = 0; i < 8; ++i) {
        int idx = base + i;
        int v = (idx < n) ? off[idx] : 0;
        s += v;
        loc[i] = s;
    }
    red[t] = s;
    __syncthreads();
    #pragma unroll
    for (int o = 1; o < 256; o <<= 1) {
        int u = (t >= o) ? red[t - o] : 0;
        __syncthreads();
        red[t] += u;
        __syncthreads();
    }
    int offset = part[blockIdx.x] + red[t] - s;
    #pragma unroll
    for (int i = 0; i < 8; ++i) {
        int idx = base + i;
        if (idx < n) off[idx] = loc[i] + offset;
    }
}

__global__ void gin_fill_kernel(const int* __restrict__ src, const int* __restrict__ dst,
                                int* __restrict__ off, int* __restrict__ csr, int E) {
    int e = blockIdx.x * 256 + threadIdx.x;
    if (e < E) {
        int d = dst[e];
        int p = atomicAdd(&off[d], 1);
        csr[p] = src[e];
    }
}

// descending bin bases: cursor[b] = sum_{b' > b} hist[b'] (single wave of 64)
__global__ void gin_binbase_kernel(const int* __restrict__ hist, int* __restrict__ cursor) {
    int t = threadIdx.x;  // 0..63
    int v = hist[t];
    int s = v;
    #pragma unroll
    for (int o = 1; o < 64; o <<= 1) {
        int u = __shfl_up(s, o, 64);
        if (t >= o) s += u;
    }
    int total = __shfl(s, 63, 64);
    cursor[t] = total - s;   // suffix sum: higher degree first
}

__global__ void gin_permfill_kernel(const int* __restrict__ offend, int* __restrict__ cursor,
                                    int* __restrict__ perm, int n) {
    __shared__ int lh[64];
    __shared__ int lbase[64];
    int t = threadIdx.x;
    if (t < 64) lh[t] = 0;
    __syncthreads();
    int i = blockIdx.x * 256 + t;
    int d = 0, rank = 0;
    if (i < n) {
        d = min(offend[i] - (i ? offend[i - 1] : 0), 63);
        rank = atomicAdd(&lh[d], 1);
    }
    __syncthreads();
    if (t < 64 && lh[t]) lbase[t] = atomicAdd(&cursor[t], lh[t]);
    __syncthreads();
    if (i < n) perm[lbase[d] + rank] = i;
}

// ---------------- fused GINConv layer: pipelined batched gather + MLP ----------------
// Round-13 body, 128-node blocks: 512 threads = 8 INDEPENDENT waves, 16 nodes
// each (no barriers, no shared state; wave-private scratch). Rationale: block
// size 16->64 nodes cut HBM FETCH 106->87MB (tighter temporal clustering of the
// random gather window); probing 128. Slot s -> node perm[s] (descending-degree
// sort). Thread l=(lg,lr) gathers node perm[m0+lr], channels lg*8+{0..7}+32*kc,
// straight into MFMA A-fragments; batch-4 edges with software-pipelined csr
// prefetch. Self-row loads at the END (hoisting regressed: VGPR spill, r18).
template <int N1, int N2, typename OutT>
__global__ __launch_bounds__(512, 4)
void gin_fused(const __half* __restrict__ Hin, const int* __restrict__ offend,
               const int* __restrict__ csr, const int* __restrict__ perm,
               const float* __restrict__ eps_p, int layer,
               const unsigned short* __restrict__ PW1, const float* __restrict__ B1,
               const unsigned short* __restrict__ PW2, const float* __restrict__ B2,
               OutT* __restrict__ Out, int nrows) {
    constexpr int K1 = 128;
    constexpr int KC1 = K1 / 32, NT1 = N1 / 16, KC2 = N1 / 32, NT2 = N2 / 16;
    constexpr int SS = 36;    // scratch f32 row stride
    __shared__ __align__(16) float Scr[8 * 16 * SS];

    const int tid = threadIdx.x;
    const int w = tid >> 6;   // 0..7
    const int l = tid & 63;
    const int lr = l & 15;   // slot/row within wave band; A-row / B-col / C-col
    const int lg = l >> 4;   // k-group; A-k = kc*32+lg*8+j; C-row = lg*4+r
    const int m0 = blockIdx.x * 128 + w * 16;
    const int slot = m0 + lr;
    float* sw = &Scr[w * 16 * SS];

    // ---- phase 1: gather z-fragment in registers ----
    union { bf16x8 v; unsigned short u[8]; } AH[KC1], AL[KC1];

    if (slot < nrows) {
        const int node = perm[slot];
        int lo = node ? offend[node - 1] : 0;
        int hi = offend[node];
        float s[KC1][8];
        #pragma unroll
        for (int kc = 0; kc < KC1; ++kc)
            #pragma unroll
            for (int j = 0; j < 8; ++j) s[kc][j] = 0.f;

        const size_t coff = (size_t)lg * 8;   // channel offset of this thread's slots
        int e = lo;
        const int him1 = hi - 1;
        int i0 = 0, i1 = 0, i2 = 0, i3 = 0;
        if (e < hi) {
            i0 = csr[min(e,     him1)];
            i1 = csr[min(e + 1, him1)];
            i2 = csr[min(e + 2, him1)];
            i3 = csr[min(e + 3, him1)];
        }
        // batch-4, software-pipelined: prefetch next indices during gather
        while (e + 3 < hi) {
            int c0 = i0, c1 = i1, c2 = i2, c3 = i3;
            e += 4;
            i0 = csr[min(e,     him1)];
            i1 = csr[min(e + 1, him1)];
            i2 = csr[min(e + 2, him1)];
            i3 = csr[min(e + 3, him1)];
            const uint4* p0 = (const uint4*)(Hin + (size_t)c0 * NCH + coff);
            const uint4* p1 = (const uint4*)(Hin + (size_t)c1 * NCH + coff);
            const uint4* p2 = (const uint4*)(Hin + (size_t)c2 * NCH + coff);
            const uint4* p3 = (const uint4*)(Hin + (size_t)c3 * NCH + coff);
            uint4 r0[KC1], r1[KC1], r2[KC1], r3[KC1];
            #pragma unroll
            for (int kc = 0; kc < KC1; ++kc) {
                r0[kc] = p0[kc * 4]; r1[kc] = p1[kc * 4];
                r2[kc] = p2[kc * 4]; r3[kc] = p3[kc * 4];
            }
            #pragma unroll
            for (int kc = 0; kc < KC1; ++kc) {
                const __half2* h0 = (const __half2*)&r0[kc];
                const __half2* h1 = (const __half2*)&r1[kc];
                const __half2* h2 = (const __half2*)&r2[kc];
                const __half2* h3 = (const __half2*)&r3[kc];
                #pragma unroll
                for (int j = 0; j < 4; ++j) {
                    float2 f0 = __half22float2(h0[j]);
                    float2 f1 = __half22float2(h1[j]);
                    float2 f2 = __half22float2(h2[j]);
                    float2 f3 = __half22float2(h3[j]);
                    s[kc][j * 2]     += (f0.x + f1.x) + (f2.x + f3.x);
                    s[kc][j * 2 + 1] += (f0.y + f1.y) + (f2.y + f3.y);
                }
            }
        }
        // pair tail
        for (; e + 1 < hi; e += 2) {
            int a0 = csr[e], a1 = csr[e + 1];
            const uint4* p0 = (const uint4*)(Hin + (size_t)a0 * NCH + coff);
            const uint4* p1 = (const uint4*)(Hin + (size_t)a1 * NCH + coff);
            uint4 r0[KC1], r1[KC1];
            #pragma unroll
            for (int kc = 0; kc < KC1; ++kc) { r0[kc] = p0[kc * 4]; r1[kc] = p1[kc * 4]; }
            #pragma unroll
            for (int kc = 0; kc < KC1; ++kc) {
                const __half2* h0 = (const __half2*)&r0[kc];
                const __half2* h1 = (const __half2*)&r1[kc];
                #pragma unroll
                for (int j = 0; j < 4; ++j) {
                    float2 f0 = __half22float2(h0[j]);
                    float2 f1 = __half22float2(h1[j]);
                    s[kc][j * 2]     += f0.x + f1.x;
                    s[kc][j * 2 + 1] += f0.y + f1.y;
                }
            }
        }
        if (e < hi) {
            const uint4* p0 = (const uint4*)(Hin + (size_t)csr[e] * NCH + coff);
            uint4 r0[KC1];
            #pragma unroll
            for (int kc = 0; kc < KC1; ++kc) r0[kc] = p0[kc * 4];
            #pragma unroll
            for (int kc = 0; kc < KC1; ++kc) {
                const __half2* h0 = (const __half2*)&r0[kc];
                #pragma unroll
                for (int j = 0; j < 4; ++j) {
                    float2 f0 = __half22float2(h0[j]);
                    s[kc][j * 2]     += f0.x;
                    s[kc][j * 2 + 1] += f0.y;
                }
            }
        }
        float invd = 1.0f / fmaxf((float)(hi - lo), 1.0f);
        float e1 = 1.0f + eps_p[layer];
        const uint4* ps = (const uint4*)(Hin + (size_t)node * NCH + coff);
        #pragma unroll
        for (int kc = 0; kc < KC1; ++kc) {
            uint4 rs = ps[kc * 4];
            const __half2* hs = (const __half2*)&rs;
            #pragma unroll
            for (int j = 0; j < 4; ++j) {
                float2 fs = __half22float2(hs[j]);
                float z0 = e1 * fs.x + s[kc][j * 2] * invd;
                float z1 = e1 * fs.y + s[kc][j * 2 + 1] * invd;
                split_bf16(z0, AH[kc].u[j * 2], AL[kc].u[j * 2]);
                split_bf16(z1, AH[kc].u[j * 2 + 1], AL[kc].u[j * 2 + 1]);
            }
        }
    } else {
        #pragma unroll
        for (int kc = 0; kc < KC1; ++kc) {
            AH[kc].v = (bf16x8){0,0,0,0,0,0,0,0};
            AL[kc].v = (bf16x8){0,0,0,0,0,0,0,0};
        }
    }

    // ---- GEMM1: T = leaky(Z @ W1 + b1) ----
    f32x4 acc[NT1];
    #pragma unroll
    for (int nt = 0; nt < NT1; ++nt) acc[nt] = {0.f, 0.f, 0.f, 0.f};

    #pragma unroll
    for (int kc = 0; kc < KC1; ++kc) {
        #pragma unroll
        for (int nt = 0; nt < NT1; ++nt) {
            const unsigned short* pb = PW1 + (((size_t)kc * NT1 + nt) * 64 + l) * 8;
            bf16x8 bh = *(const bf16x8*)pb;
            bf16x8 bl = *(const bf16x8*)(pb + (size_t)KC1 * NT1 * 512);
            acc[nt] = __builtin_amdgcn_mfma_f32_16x16x32_bf16(AH[kc].v, bh, acc[nt], 0, 0, 0);
            acc[nt] = __builtin_amdgcn_mfma_f32_16x16x32_bf16(AH[kc].v, bl, acc[nt], 0, 0, 0);
            acc[nt] = __builtin_amdgcn_mfma_f32_16x16x32_bf16(AL[kc].v, bh, acc[nt], 0, 0, 0);
        }
    }

    // ---- GEMM2 interleaved with epilogue-1 via wave-private scratch (no barrier) ----
    f32x4 acc2[NT2];
    #pragma unroll
    for (int nt = 0; nt < NT2; ++nt) acc2[nt] = {0.f, 0.f, 0.f, 0.f};

    #pragma unroll
    for (int kc = 0; kc < KC2; ++kc) {
        #pragma unroll
        for (int t = 0; t < 2; ++t) {
            int nt = kc * 2 + t;
            float bb = B1[nt * 16 + lr];
            #pragma unroll
            for (int r = 0; r < 4; ++r) {
                float v = acc[nt][r] + bb;
                v = v > 0.f ? v : 0.01f * v;
                sw[(lg * 4 + r) * SS + t * 16 + lr] = v;
            }
        }
        const float* tp = &sw[lr * SS + lg * 8];
        f32x4 v0 = *(const f32x4*)tp;
        f32x4 v1 = *(const f32x4*)(tp + 4);
        union { bf16x8 v; unsigned short u[8]; } H, L;
        #pragma unroll
        for (int i = 0; i < 4; ++i) {
            split_bf16(v0[i], H.u[i], L.u[i]);
            split_bf16(v1[i], H.u[i + 4], L.u[i + 4]);
        }
        bf16x8 ah = H.v, al = L.v;
        #pragma unroll
        for (int nt = 0; nt < NT2; ++nt) {
            const unsigned short* pb = PW2 + (((size_t)kc * NT2 + nt) * 64 + l) * 8;
            bf16x8 bh = *(const bf16x8*)pb;
            bf16x8 bl = *(const bf16x8*)(pb + (size_t)KC2 * NT2 * 512);
            acc2[nt] = __builtin_amdgcn_mfma_f32_16x16x32_bf16(ah, bh, acc2[nt], 0, 0, 0);
            acc2[nt] = __builtin_amdgcn_mfma_f32_16x16x32_bf16(ah, bl, acc2[nt], 0, 0, 0);
            acc2[nt] = __builtin_amdgcn_mfma_f32_16x16x32_bf16(al, bh, acc2[nt], 0, 0, 0);
        }
    }

    // epilogue 2: bias + leaky -> global rows perm[m0+lg*4+r]
    int onode[4];
    #pragma unroll
    for (int r = 0; r < 4; ++r) {
        int s2 = m0 + lg * 4 + r;
        onode[r] = (s2 < nrows) ? perm[s2] : -1;
    }
    #pragma unroll
    for (int nt = 0; nt < NT2; ++nt) {
        float bb = B2[nt * 16 + lr];
        #pragma unroll
        for (int r = 0; r < 4; ++r) {
            if (onode[r] >= 0) {
                float v = acc2[nt][r] + bb;
                v = v > 0.f ? v : 0.01f * v;
                Out[(size_t)onode[r] * N2 + nt * 16 + lr] = (OutT)v;
            }
        }
    }
}

// ---------------- launch ----------------

extern "C" void kernel_launch(void* const* d_in, const int* in_sizes, int n_in,
                              void* d_out, int out_size, void* d_ws, size_t ws_size,
                              hipStream_t stream) {
    const float* x   = (const float*)d_in[0];
    const int*   src = (const int*)d_in[1];
    const int*   dst = (const int*)d_in[2];
    const float* eps = (const float*)d_in[3];
    const float* w1s = (const float*)d_in[4];
    const float* b1s = (const float*)d_in[5];
    const float* w2s = (const float*)d_in[6];
    const float* b2s = (const float*)d_in[7];
    const float* wf1 = (const float*)d_in[8];
    const float* bf1 = (const float*)d_in[9];
    const float* wf2 = (const float*)d_in[10];
    const float* bf2 = (const float*)d_in[11];

    const int N = in_sizes[0] / NCH;   // 100000
    const int E = in_sizes[1];         // 600000

    auto align256 = [](size_t v) { return (v + 255) & ~(size_t)255; };
    char* p = (char*)d_ws;
    int* off = (int*)p;              p += align256((size_t)(N + 1) * 4);
    int* hist = (int*)p;             p += align256(64 * 4);     // adjacent to off: one memset
    int* part = (int*)p;             p += align256(1024 * 4);
    int* cursor = (int*)p;           p += align256(64 * 4);
    int* perm = (int*)p;             p += align256((size_t)N * 4);
    int* csr = (int*)p;              p += align256((size_t)E * 4);
    __half* xh = (__half*)p;         p += align256((size_t)N * NCH * 2);
    __half* h0 = (__half*)p;         p += align256((size_t)N * NCH * 2);
    __half* h1 = (__half*)p;         p += align256((size_t)N * NCH * 2);
    unsigned short* pw1 = (unsigned short*)p; p += 3 * 65536;
    unsigned short* pw2 = (unsigned short*)p; p += 3 * 65536;
    unsigned short* pwf1 = (unsigned short*)p; p += 32768;
    unsigned short* pwf2 = (unsigned short*)p;

    // one memset covers off (+pad) + hist
    const int nScan = N + 1;
    const int nTiles = (nScan + 2047) / 2048;
    hipMemsetAsync(off, 0, align256((size_t)nScan * 4) + 64 * 4, stream);

    // fused prep: f2h + deg + packall in one launch
    const int n4 = N * NCH / 4;
    const int n4b = (n4 + 255) / 256;
    const int degb = (E + 255) / 256;
    const int packb = (221184 + 255) / 256;
    gin_prep_kernel<<<n4b + degb + packb, 256, 0, stream>>>(
        x, xh, n4b, n4, dst, off, degb, E,
        w1s, w2s, wf1, wf2, pw1, pw2, pwf1, pwf2);

    gin_scan1<<<nTiles, 256, 0, stream>>>(off, part, hist, nScan);   // + degree histogram
    gin_scan2<<<1, 256, 0, stream>>>(part, nTiles);
    gin_scan3<<<nTiles, 256, 0, stream>>>(off, part, nScan);
    gin_fill_kernel<<<(E + 255) / 256, 256, 0, stream>>>(src, dst, off, csr, E);

    // descending-degree permutation
    gin_binbase_kernel<<<1, 64, 0, stream>>>(hist, cursor);
    gin_permfill_kernel<<<(N + 255) / 256, 256, 0, stream>>>(off, cursor, perm, N);

    const int grid = (N + 127) / 128;   // 8-wave blocks, 128 nodes each

    // layer 0: xh -> h0
    gin_fused<128, 128, __half><<<grid, 512, 0, stream>>>(
        xh, off, csr, perm, eps, 0, pw1, b1s, pw2, b2s, h0, N);
    // layer 1: h0 -> h1
    gin_fused<128, 128, __half><<<grid, 512, 0, stream>>>(
        h0, off, csr, perm, eps, 1, pw1 + 32768, b1s + 128, pw2 + 32768, b2s + 128, h1, N);
    // layer 2: h1 -> h0
    gin_fused<128, 128, __half><<<grid, 512, 0, stream>>>(
        h1, off, csr, perm, eps, 2, pw1 + 65536, b1s + 256, pw2 + 65536, b2s + 256, h0, N);
    // final layer: h0 -> d_out (128 -> 64 -> 64, f32)
    gin_fused<64, 64, float><<<grid, 512, 0, stream>>>(
        h0, off, csr, perm, eps, 3, pwf1, bf1, pwf2, bf2, (float*)d_out, N);
}

// Round 21
// 336.795 us; speedup vs baseline: 1.0604x; 1.0604x over previous
//
#include <hip/hip_runtime.h>
#include <hip/hip_fp16.h>

#define NCH 128

typedef short bf16x8 __attribute__((ext_vector_type(8)));
typedef float f32x4 __attribute__((ext_vector_type(4)));

__device__ __forceinline__ unsigned short f32_to_bf16_rne(float f) {
    unsigned u = __float_as_uint(f);
    unsigned r = u + 0x7FFFu + ((u >> 16) & 1u);
    return (unsigned short)(r >> 16);
}
// trunc-split: hi = trunc16(f), lo = rne(f - hi). |lo| <= 2^-8|f|.
__device__ __forceinline__ void split_bf16(float f, unsigned short& hi, unsigned short& lo) {
    unsigned u = __float_as_uint(f);
    hi = (unsigned short)(u >> 16);
    float l = f - __uint_as_float(u & 0xFFFF0000u);
    lo = f32_to_bf16_rne(l);
}

// ---------------- fused prep: f2h + degree-count + weight-pack in ONE launch ----------------
// Three fully independent jobs (disjoint outputs) routed by blockIdx range.
__global__ void gin_prep_kernel(const float* __restrict__ x, __half* __restrict__ xh,
                                int n4b, int n4,
                                const int* __restrict__ dst, int* __restrict__ off,
                                int degb, int E,
                                const float* __restrict__ w1s, const float* __restrict__ w2s,
                                const float* __restrict__ wf1, const float* __restrict__ wf2,
                                unsigned short* __restrict__ pw1, unsigned short* __restrict__ pw2,
                                unsigned short* __restrict__ pwf1, unsigned short* __restrict__ pwf2) {
    int b = blockIdx.x;
    int t = threadIdx.x;
    if (b < n4b) {
        int i = b * 256 + t;
        if (i < n4) {
            float4 v = ((const float4*)x)[i];
            union { __half h[4]; uint2 u; } o;
            o.h[0] = __float2half(v.x); o.h[1] = __float2half(v.y);
            o.h[2] = __float2half(v.z); o.h[3] = __float2half(v.w);
            ((uint2*)xh)[i] = o.u;
        }
        return;
    }
    b -= n4b;
    if (b < degb) {
        int e = b * 256 + t;
        if (e < E) atomicAdd(&off[dst[e] + 1], 1);
        return;
    }
    b -= degb;
    int idx = b * 256 + t;
    const float* W; unsigned short* out; int K, N, e;
    if (idx < 98304) {
        int layer = idx >> 15; e = idx & 32767;
        W = w1s + (size_t)layer * 16384; out = pw1 + (size_t)layer * 32768; K = 128; N = 128;
    } else if (idx < 196608) {
        int j = idx - 98304; int layer = j >> 15; e = j & 32767;
        W = w2s + (size_t)layer * 16384; out = pw2 + (size_t)layer * 32768; K = 128; N = 128;
    } else if (idx < 212992) {
        e = idx - 196608; W = wf1; out = pwf1; K = 128; N = 64;
    } else if (idx < 221184) {
        e = idx - 212992; W = wf2; out = pwf2; K = 64; N = 64;
    } else return;
    int KC = K / 32, NT = N / 16;
    int j = e & 7;
    int l = (e >> 3) & 63;
    int v = e >> 9;
    int nt = v % NT; v /= NT;
    int kc = v % KC;
    int spl = v / KC;
    int k = kc * 32 + (l >> 4) * 8 + j;
    int n = nt * 16 + (l & 15);
    float w = W[(size_t)k * N + n];
    unsigned short hi, lo;
    split_bf16(w, hi, lo);
    out[e] = (spl == 0) ? hi : lo;
}

// ---------------- CSR scan (off[d] = start of node d; fill makes it inclusive end) ----------------

// scan1 + degree histogram fused (off[idx] pre-scan IS degree of node idx-1 for idx>=1)
__global__ void gin_scan1(const int* __restrict__ off, int* __restrict__ part,
                          int* __restrict__ hist, int n) {
    __shared__ int red[256];
    __shared__ int lh[64];
    int t = threadIdx.x;
    if (t < 64) lh[t] = 0;
    __syncthreads();
    int base = blockIdx.x * 2048 + t * 8;
    int s = 0;
    for (int i = 0; i < 8; ++i) {
        int idx = base + i;
        if (idx < n) {
            int v = off[idx];
            s += v;
            if (idx > 0) atomicAdd(&lh[min(v, 63)], 1);
        }
    }
    red[t] = s;
    __syncthreads();
    #pragma unroll
    for (int o = 128; o > 0; o >>= 1) {
        if (t < o) red[t] += red[t + o];
        __syncthreads();
    }
    if (t == 0) part[blockIdx.x] = red[0];
    if (t < 64 && lh[t]) atomicAdd(&hist[t], lh[t]);
}

// exclusive scan of part[0..nb-1] in place (nb <= 256)
__global__ void gin_scan2(int* __restrict__ part, int nb) {
    __shared__ int sh[256];
    int t = threadIdx.x;
    int v = (t < nb) ? part[t] : 0;
    sh[t] = v;
    __syncthreads();
    #pragma unroll
    for (int o = 1; o < 256; o <<= 1) {
        int u = (t >= o) ? sh[t - o] : 0;
        __syncthreads();
        sh[t] += u;
        __syncthreads();
    }
    if (t < nb) part[t] = sh[t] - v;
}

__global__ void gin_scan3(int* __restrict__ off, const int* __restrict__ part, int n) {
    __shared__ int red[256];
    int t = threadIdx.x;
    int base = blockIdx.x * 2048 + t * 8;
    int loc[8];
    int s = 0;
    #pragma unroll
    for (int i = 0; i < 8; ++i) {
        int idx = base + i;
        int v = (idx < n) ? off[idx] : 0;
        s += v;
        loc[i] = s;
    }
    red[t] = s;
    __syncthreads();
    #pragma unroll
    for (int o = 1; o < 256; o <<= 1) {
        int u = (t >= o) ? red[t - o] : 0;
        __syncthreads();
        red[t] += u;
        __syncthreads();
    }
    int offset = part[blockIdx.x] + red[t] - s;
    #pragma unroll
    for (int i = 0; i < 8; ++i) {
        int idx = base + i;
        if (idx < n) off[idx] = loc[i] + offset;
    }
}

__global__ void gin_fill_kernel(const int* __restrict__ src, const int* __restrict__ dst,
                                int* __restrict__ off, int* __restrict__ csr, int E) {
    int e = blockIdx.x * 256 + threadIdx.x;
    if (e < E) {
        int d = dst[e];
        int p = atomicAdd(&off[d], 1);
        csr[p] = src[e];
    }
}

// descending bin bases: cursor[b] = sum_{b' > b} hist[b'] (single wave of 64)
__global__ void gin_binbase_kernel(const int* __restrict__ hist, int* __restrict__ cursor) {
    int t = threadIdx.x;  // 0..63
    int v = hist[t];
    int s = v;
    #pragma unroll
    for (int o = 1; o < 64; o <<= 1) {
        int u = __shfl_up(s, o, 64);
        if (t >= o) s += u;
    }
    int total = __shfl(s, 63, 64);
    cursor[t] = total - s;   // suffix sum: higher degree first
}

__global__ void gin_permfill_kernel(const int* __restrict__ offend, int* __restrict__ cursor,
                                    int* __restrict__ perm, int n) {
    __shared__ int lh[64];
    __shared__ int lbase[64];
    int t = threadIdx.x;
    if (t < 64) lh[t] = 0;
    __syncthreads();
    int i = blockIdx.x * 256 + t;
    int d = 0, rank = 0;
    if (i < n) {
        d = min(offend[i] - (i ? offend[i - 1] : 0), 63);
        rank = atomicAdd(&lh[d], 1);
    }
    __syncthreads();
    if (t < 64 && lh[t]) lbase[t] = atomicAdd(&cursor[t], lh[t]);
    __syncthreads();
    if (i < n) perm[lbase[d] + rank] = i;
}

// ---------------- fused GINConv layer: pipelined batched gather + MLP ----------------
// Round-13 configuration, byte-for-byte (twice-measured optimum: 74.5us/dispatch).
// 256 threads = 4 waves, 16 slots/wave, 64 nodes/block (block-size curve measured:
// 16-node = 106MB FETCH/80.7us, 64 = 87MB/74.5us, 128 = 87MB/78us -> 64 optimal).
// Slot s -> node perm[s] (descending-degree sort: uniform lane degrees + LPT).
// Thread l=(lg,lr) gathers node perm[m0+lr], channels lg*8+{0..7}+32*kc, straight
// into MFMA A-fragments; batch-4 edges with software-pipelined csr prefetch.
// Self-row loads at the END (hoisting regressed: VGPR spill, r18). No setprio
// (neutral-negative, r16). GEMM1->GEMM2 via wave-private LDS scratch (no barriers).
template <int N1, int N2, typename OutT>
__global__ __launch_bounds__(256, 4)
void gin_fused(const __half* __restrict__ Hin, const int* __restrict__ offend,
               const int* __restrict__ csr, const int* __restrict__ perm,
               const float* __restrict__ eps_p, int layer,
               const unsigned short* __restrict__ PW1, const float* __restrict__ B1,
               const unsigned short* __restrict__ PW2, const float* __restrict__ B2,
               OutT* __restrict__ Out, int nrows) {
    constexpr int K1 = 128;
    constexpr int KC1 = K1 / 32, NT1 = N1 / 16, KC2 = N1 / 32, NT2 = N2 / 16;
    constexpr int SS = 36;    // scratch f32 row stride
    __shared__ __align__(16) float Scr[4 * 16 * SS];

    const int tid = threadIdx.x;
    const int w = tid >> 6;
    const int l = tid & 63;
    const int lr = l & 15;   // slot/row within wave band; A-row / B-col / C-col
    const int lg = l >> 4;   // k-group; A-k = kc*32+lg*8+j; C-row = lg*4+r
    const int m0 = blockIdx.x * 64 + w * 16;
    const int slot = m0 + lr;
    float* sw = &Scr[w * 16 * SS];

    // ---- phase 1: gather z-fragment in registers ----
    union { bf16x8 v; unsigned short u[8]; } AH[KC1], AL[KC1];

    if (slot < nrows) {
        const int node = perm[slot];
        int lo = node ? offend[node - 1] : 0;
        int hi = offend[node];
        float s[KC1][8];
        #pragma unroll
        for (int kc = 0; kc < KC1; ++kc)
            #pragma unroll
            for (int j = 0; j < 8; ++j) s[kc][j] = 0.f;

        const size_t coff = (size_t)lg * 8;   // channel offset of this thread's slots
        int e = lo;
        const int him1 = hi - 1;
        int i0 = 0, i1 = 0, i2 = 0, i3 = 0;
        if (e < hi) {
            i0 = csr[min(e,     him1)];
            i1 = csr[min(e + 1, him1)];
            i2 = csr[min(e + 2, him1)];
            i3 = csr[min(e + 3, him1)];
        }
        // batch-4, software-pipelined: prefetch next indices during gather
        while (e + 3 < hi) {
            int c0 = i0, c1 = i1, c2 = i2, c3 = i3;
            e += 4;
            i0 = csr[min(e,     him1)];
            i1 = csr[min(e + 1, him1)];
            i2 = csr[min(e + 2, him1)];
            i3 = csr[min(e + 3, him1)];
            const uint4* p0 = (const uint4*)(Hin + (size_t)c0 * NCH + coff);
            const uint4* p1 = (const uint4*)(Hin + (size_t)c1 * NCH + coff);
            const uint4* p2 = (const uint4*)(Hin + (size_t)c2 * NCH + coff);
            const uint4* p3 = (const uint4*)(Hin + (size_t)c3 * NCH + coff);
            uint4 r0[KC1], r1[KC1], r2[KC1], r3[KC1];
            #pragma unroll
            for (int kc = 0; kc < KC1; ++kc) {
                r0[kc] = p0[kc * 4]; r1[kc] = p1[kc * 4];
                r2[kc] = p2[kc * 4]; r3[kc] = p3[kc * 4];
            }
            #pragma unroll
            for (int kc = 0; kc < KC1; ++kc) {
                const __half2* h0 = (const __half2*)&r0[kc];
                const __half2* h1 = (const __half2*)&r1[kc];
                const __half2* h2 = (const __half2*)&r2[kc];
                const __half2* h3 = (const __half2*)&r3[kc];
                #pragma unroll
                for (int j = 0; j < 4; ++j) {
                    float2 f0 = __half22float2(h0[j]);
                    float2 f1 = __half22float2(h1[j]);
                    float2 f2 = __half22float2(h2[j]);
                    float2 f3 = __half22float2(h3[j]);
                    s[kc][j * 2]     += (f0.x + f1.x) + (f2.x + f3.x);
                    s[kc][j * 2 + 1] += (f0.y + f1.y) + (f2.y + f3.y);
                }
            }
        }
        // pair tail
        for (; e + 1 < hi; e += 2) {
            int a0 = csr[e], a1 = csr[e + 1];
            const uint4* p0 = (const uint4*)(Hin + (size_t)a0 * NCH + coff);
            const uint4* p1 = (const uint4*)(Hin + (size_t)a1 * NCH + coff);
            uint4 r0[KC1], r1[KC1];
            #pragma unroll
            for (int kc = 0; kc < KC1; ++kc) { r0[kc] = p0[kc * 4]; r1[kc] = p1[kc * 4]; }
            #pragma unroll
            for (int kc = 0; kc < KC1; ++kc) {
                const __half2* h0 = (const __half2*)&r0[kc];
                const __half2* h1 = (const __half2*)&r1[kc];
                #pragma unroll
                for (int j = 0; j < 4; ++j) {
                    float2 f0 = __half22float2(h0[j]);
                    float2 f1 = __half22float2(h1[j]);
                    s[kc][j * 2]     += f0.x + f1.x;
                    s[kc][j * 2 + 1] += f0.y + f1.y;
                }
            }
        }
        if (e < hi) {
            const uint4* p0 = (const uint4*)(Hin + (size_t)csr[e] * NCH + coff);
            uint4 r0[KC1];
            #pragma unroll
            for (int kc = 0; kc < KC1; ++kc) r0[kc] = p0[kc * 4];
            #pragma unroll
            for (int kc = 0; kc < KC1; ++kc) {
                const __half2* h0 = (const __half2*)&r0[kc];
                #pragma unroll
                for (int j = 0; j < 4; ++j) {
                    float2 f0 = __half22float2(h0[j]);
                    s[kc][j * 2]     += f0.x;
                    s[kc][j * 2 + 1] += f0.y;
                }
            }
        }
        float invd = 1.0f / fmaxf((float)(hi - lo), 1.0f);
        float e1 = 1.0f + eps_p[layer];
        const uint4* ps = (const uint4*)(Hin + (size_t)node * NCH + coff);
        #pragma unroll
        for (int kc = 0; kc < KC1; ++kc) {
            uint4 rs = ps[kc * 4];
            const __half2* hs = (const __half2*)&rs;
            #pragma unroll
            for (int j = 0; j < 4; ++j) {
                float2 fs = __half22float2(hs[j]);
                float z0 = e1 * fs.x + s[kc][j * 2] * invd;
                float z1 = e1 * fs.y + s[kc][j * 2 + 1] * invd;
                split_bf16(z0, AH[kc].u[j * 2], AL[kc].u[j * 2]);
                split_bf16(z1, AH[kc].u[j * 2 + 1], AL[kc].u[j * 2 + 1]);
            }
        }
    } else {
        #pragma unroll
        for (int kc = 0; kc < KC1; ++kc) {
            AH[kc].v = (bf16x8){0,0,0,0,0,0,0,0};
            AL[kc].v = (bf16x8){0,0,0,0,0,0,0,0};
        }
    }

    // ---- GEMM1: T = leaky(Z @ W1 + b1) ----
    f32x4 acc[NT1];
    #pragma unroll
    for (int nt = 0; nt < NT1; ++nt) acc[nt] = {0.f, 0.f, 0.f, 0.f};

    #pragma unroll
    for (int kc = 0; kc < KC1; ++kc) {
        #pragma unroll
        for (int nt = 0; nt < NT1; ++nt) {
            const unsigned short* pb = PW1 + (((size_t)kc * NT1 + nt) * 64 + l) * 8;
            bf16x8 bh = *(const bf16x8*)pb;
            bf16x8 bl = *(const bf16x8*)(pb + (size_t)KC1 * NT1 * 512);
            acc[nt] = __builtin_amdgcn_mfma_f32_16x16x32_bf16(AH[kc].v, bh, acc[nt], 0, 0, 0);
            acc[nt] = __builtin_amdgcn_mfma_f32_16x16x32_bf16(AH[kc].v, bl, acc[nt], 0, 0, 0);
            acc[nt] = __builtin_amdgcn_mfma_f32_16x16x32_bf16(AL[kc].v, bh, acc[nt], 0, 0, 0);
        }
    }

    // ---- GEMM2 interleaved with epilogue-1 via wave-private scratch (no barrier) ----
    f32x4 acc2[NT2];
    #pragma unroll
    for (int nt = 0; nt < NT2; ++nt) acc2[nt] = {0.f, 0.f, 0.f, 0.f};

    #pragma unroll
    for (int kc = 0; kc < KC2; ++kc) {
        #pragma unroll
        for (int t = 0; t < 2; ++t) {
            int nt = kc * 2 + t;
            float bb = B1[nt * 16 + lr];
            #pragma unroll
            for (int r = 0; r < 4; ++r) {
                float v = acc[nt][r] + bb;
                v = v > 0.f ? v : 0.01f * v;
                sw[(lg * 4 + r) * SS + t * 16 + lr] = v;
            }
        }
        const float* tp = &sw[lr * SS + lg * 8];
        f32x4 v0 = *(const f32x4*)tp;
        f32x4 v1 = *(const f32x4*)(tp + 4);
        union { bf16x8 v; unsigned short u[8]; } H, L;
        #pragma unroll
        for (int i = 0; i < 4; ++i) {
            split_bf16(v0[i], H.u[i], L.u[i]);
            split_bf16(v1[i], H.u[i + 4], L.u[i + 4]);
        }
        bf16x8 ah = H.v, al = L.v;
        #pragma unroll
        for (int nt = 0; nt < NT2; ++nt) {
            const unsigned short* pb = PW2 + (((size_t)kc * NT2 + nt) * 64 + l) * 8;
            bf16x8 bh = *(const bf16x8*)pb;
            bf16x8 bl = *(const bf16x8*)(pb + (size_t)KC2 * NT2 * 512);
            acc2[nt] = __builtin_amdgcn_mfma_f32_16x16x32_bf16(ah, bh, acc2[nt], 0, 0, 0);
            acc2[nt] = __builtin_amdgcn_mfma_f32_16x16x32_bf16(ah, bl, acc2[nt], 0, 0, 0);
            acc2[nt] = __builtin_amdgcn_mfma_f32_16x16x32_bf16(al, bh, acc2[nt], 0, 0, 0);
        }
    }

    // epilogue 2: bias + leaky -> global rows perm[m0+lg*4+r]
    int onode[4];
    #pragma unroll
    for (int r = 0; r < 4; ++r) {
        int s2 = m0 + lg * 4 + r;
        onode[r] = (s2 < nrows) ? perm[s2] : -1;
    }
    #pragma unroll
    for (int nt = 0; nt < NT2; ++nt) {
        float bb = B2[nt * 16 + lr];
        #pragma unroll
        for (int r = 0; r < 4; ++r) {
            if (onode[r] >= 0) {
                float v = acc2[nt][r] + bb;
                v = v > 0.f ? v : 0.01f * v;
                Out[(size_t)onode[r] * N2 + nt * 16 + lr] = (OutT)v;
            }
        }
    }
}

// ---------------- launch ----------------

extern "C" void kernel_launch(void* const* d_in, const int* in_sizes, int n_in,
                              void* d_out, int out_size, void* d_ws, size_t ws_size,
                              hipStream_t stream) {
    const float* x   = (const float*)d_in[0];
    const int*   src = (const int*)d_in[1];
    const int*   dst = (const int*)d_in[2];
    const float* eps = (const float*)d_in[3];
    const float* w1s = (const float*)d_in[4];
    const float* b1s = (const float*)d_in[5];
    const float* w2s = (const float*)d_in[6];
    const float* b2s = (const float*)d_in[7];
    const float* wf1 = (const float*)d_in[8];
    const float* bf1 = (const float*)d_in[9];
    const float* wf2 = (const float*)d_in[10];
    const float* bf2 = (const float*)d_in[11];

    const int N = in_sizes[0] / NCH;   // 100000
    const int E = in_sizes[1];         // 600000

    auto align256 = [](size_t v) { return (v + 255) & ~(size_t)255; };
    char* p = (char*)d_ws;
    int* off = (int*)p;              p += align256((size_t)(N + 1) * 4);
    int* hist = (int*)p;             p += align256(64 * 4);     // adjacent to off: one memset
    int* part = (int*)p;             p += align256(1024 * 4);
    int* cursor = (int*)p;           p += align256(64 * 4);
    int* perm = (int*)p;             p += align256((size_t)N * 4);
    int* csr = (int*)p;              p += align256((size_t)E * 4);
    __half* xh = (__half*)p;         p += align256((size_t)N * NCH * 2);
    __half* h0 = (__half*)p;         p += align256((size_t)N * NCH * 2);
    __half* h1 = (__half*)p;         p += align256((size_t)N * NCH * 2);
    unsigned short* pw1 = (unsigned short*)p; p += 3 * 65536;
    unsigned short* pw2 = (unsigned short*)p; p += 3 * 65536;
    unsigned short* pwf1 = (unsigned short*)p; p += 32768;
    unsigned short* pwf2 = (unsigned short*)p;

    // one memset covers off (+pad) + hist
    const int nScan = N + 1;
    const int nTiles = (nScan + 2047) / 2048;
    hipMemsetAsync(off, 0, align256((size_t)nScan * 4) + 64 * 4, stream);

    // fused prep: f2h + deg + packall in one launch
    const int n4 = N * NCH / 4;
    const int n4b = (n4 + 255) / 256;
    const int degb = (E + 255) / 256;
    const int packb = (221184 + 255) / 256;
    gin_prep_kernel<<<n4b + degb + packb, 256, 0, stream>>>(
        x, xh, n4b, n4, dst, off, degb, E,
        w1s, w2s, wf1, wf2, pw1, pw2, pwf1, pwf2);

    gin_scan1<<<nTiles, 256, 0, stream>>>(off, part, hist, nScan);   // + degree histogram
    gin_scan2<<<1, 256, 0, stream>>>(part, nTiles);
    gin_scan3<<<nTiles, 256, 0, stream>>>(off, part, nScan);
    gin_fill_kernel<<<(E + 255) / 256, 256, 0, stream>>>(src, dst, off, csr, E);

    // descending-degree permutation
    gin_binbase_kernel<<<1, 64, 0, stream>>>(hist, cursor);
    gin_permfill_kernel<<<(N + 255) / 256, 256, 0, stream>>>(off, cursor, perm, N);

    const int grid = (N + 63) / 64;   // 4-wave blocks, 64 nodes each (measured optimum)

    // layer 0: xh -> h0
    gin_fused<128, 128, __half><<<grid, 256, 0, stream>>>(
        xh, off, csr, perm, eps, 0, pw1, b1s, pw2, b2s, h0, N);
    // layer 1: h0 -> h1
    gin_fused<128, 128, __half><<<grid, 256, 0, stream>>>(
        h0, off, csr, perm, eps, 1, pw1 + 32768, b1s + 128, pw2 + 32768, b2s + 128, h1, N);
    // layer 2: h1 -> h0
    gin_fused<128, 128, __half><<<grid, 256, 0, stream>>>(
        h1, off, csr, perm, eps, 2, pw1 + 65536, b1s + 256, pw2 + 65536, b2s + 256, h0, N);
    // final layer: h0 -> d_out (128 -> 64 -> 64, f32)
    gin_fused<64, 64, float><<<grid, 256, 0, stream>>>(
        h0, off, csr, perm, eps, 3, pwf1, bf1, pwf2, bf2, (float*)d_out, N);
}